// Round 1
// baseline (65440.320 us; speedup 1.0000x reference)
//
#include <hip/hip_runtime.h>
#include <stdint.h>

// ---------------------------------------------------------------------------
// RNN rollout: phase-1 teacher-forced recurrence (cell only, psi batched),
// phase-2 autoregressive (8 blocks x 16 rows, MFMA bf16, streamed weights).
// Sizes fixed: B=128, T=256, HOR=512, OBS=32, LAT=256, HID=1024.
// ---------------------------------------------------------------------------

#define BATCH 128
#define TTF   256
#define HOR   512
#define OBS   32
#define LAT   256
#define HID   1024

typedef __attribute__((ext_vector_type(8))) short short8;
typedef __attribute__((ext_vector_type(4))) float floatx4;

// ---- workspace layout (bytes) ----
#define OFF_WB1   ((size_t)0)                          // 1024x256 bf16
#define OFF_WB2   (OFF_WB1 + (size_t)HID*LAT*2)        // 1024x1024 bf16
#define OFF_WB3   (OFF_WB2 + (size_t)HID*HID*2)
#define OFF_WB4   (OFF_WB3 + (size_t)HID*HID*2)
#define OFF_WB5   (OFF_WB4 + (size_t)HID*HID*2)        // 32x1024 bf16
#define OFF_WBHH  (OFF_WB5 + (size_t)OBS*HID*2)        // 256x256 bf16
#define OFF_WBIH  (OFF_WBHH + (size_t)LAT*LAT*2)       // 256x32 bf16
#define OFF_CB    (OFF_WBIH + (size_t)LAT*OBS*2)       // 256 f32 (b_ih+b_hh)
#define OFF_WHH2  (OFF_CB + (size_t)LAT*4)             // 64x256 uint2 packed W_hh^T
#define OFF_WIH2  (OFF_WHH2 + (size_t)64*256*8)        // 8x256 uint2 packed W_ih^T
#define OFF_ZF    (OFF_WIH2 + (size_t)8*256*8)         // 128x256 f32 (z after phase 1)
#define OFF_Z     (OFF_ZF + (size_t)BATCH*LAT*4)       // 32768x256 bf16 (z_t states)

__device__ __forceinline__ uint16_t f2bf(float f) {
    uint32_t u = __float_as_uint(f);
    u += 0x7fffu + ((u >> 16) & 1u);   // RNE
    return (uint16_t)(u >> 16);
}
__device__ __forceinline__ float bflo(uint32_t u) { return __uint_as_float(u << 16); }
__device__ __forceinline__ float bfhi(uint32_t u) { return __uint_as_float(u & 0xffff0000u); }

__device__ __forceinline__ float fast_tanh(float x) {
    float ax = fabsf(x);
    float e  = __expf(-2.f * ax);
    float r  = (1.f - e) / (1.f + e);
    return copysignf(r, x);
}

// swizzled LDS address for h buffers (bf16, logical row stride 1024):
// 16B granule g = col>>3 is XORed with (row&7) -> 2 lanes/bank on ds_read_b128
__device__ __forceinline__ int hswz(int row, int col) {
    return row * 1024 + ((((col >> 3) ^ (row & 7)) << 3) | (col & 7));
}

// ---------------------------------------------------------------------------
// K0 helpers: weight conversion / packing
// ---------------------------------------------------------------------------
__global__ void k_cvt(const float* __restrict__ s, uint16_t* __restrict__ d, int n) {
    int i = blockIdx.x * 256 + threadIdx.x;
    if (i < n) d[i] = f2bf(s[i]);
}

__global__ void k_cb(const float* __restrict__ a, const float* __restrict__ b,
                     float* __restrict__ c) {
    int j = threadIdx.x;
    c[j] = a[j] + b[j];
}

// pack W^T in k4-major uint2: dst[k4*256+j] = bf16(W[j][4k4..4k4+3])
__global__ void k_pack(const float* __restrict__ w, uint2* __restrict__ dst, int klen) {
    int k4 = blockIdx.x, j = threadIdx.x;
    int k = k4 * 4;
    uint32_t a = f2bf(w[(size_t)j * klen + k + 0]);
    uint32_t b = f2bf(w[(size_t)j * klen + k + 1]);
    uint32_t c = f2bf(w[(size_t)j * klen + k + 2]);
    uint32_t d = f2bf(w[(size_t)j * klen + k + 3]);
    uint2 r; r.x = a | (b << 16); r.y = c | (d << 16);
    dst[k4 * 256 + j] = r;
}

// ---------------------------------------------------------------------------
// K1: teacher-forced recurrence. 128 blocks (1 batch row) x 256 threads.
// Stores z_t (bf16) for t=0..255 and final z (f32).
// ---------------------------------------------------------------------------
__global__ __launch_bounds__(256) void k_rnn_tf(
    const float* __restrict__ y, const uint2* __restrict__ whh2,
    const uint2* __restrict__ wih2, const float* __restrict__ cb,
    uint16_t* __restrict__ Zg, float* __restrict__ zfinal)
{
    __shared__ alignas(16) float zl[LAT];
    __shared__ alignas(16) float ys[OBS];
    int j = threadIdx.x, b = blockIdx.x;
    zl[j] = 0.f;
    __syncthreads();
    const float4* z4 = (const float4*)zl;
    const float4* y4 = (const float4*)ys;
    for (int t = 0; t < TTF; t++) {
        if (j < OBS) ys[j] = y[(size_t)b * (TTF * OBS) + t * OBS + j];
        Zg[((size_t)b * TTF + t) * LAT + j] = f2bf(zl[j]);   // store z_t (own value)
        __syncthreads();
        float acc = cb[j];
        #pragma unroll 8
        for (int k4 = 0; k4 < 64; k4++) {
            uint2 wv = whh2[k4 * 256 + j];
            float4 zq = z4[k4];
            acc += bflo(wv.x) * zq.x + bfhi(wv.x) * zq.y
                 + bflo(wv.y) * zq.z + bfhi(wv.y) * zq.w;
        }
        #pragma unroll
        for (int k4 = 0; k4 < 8; k4++) {
            uint2 wv = wih2[k4 * 256 + j];
            float4 yq = y4[k4];
            acc += bflo(wv.x) * yq.x + bfhi(wv.x) * yq.y
                 + bflo(wv.y) * yq.z + bfhi(wv.y) * yq.w;
        }
        __syncthreads();
        zl[j] = fast_tanh(acc);
    }
    __syncthreads();
    zfinal[(size_t)b * LAT + j] = zl[j];
}

// ---------------------------------------------------------------------------
// K2: bulk psi over all 32768 phase-1 states. 1024 blocks x 32 rows, 512 thr.
// ---------------------------------------------------------------------------
__global__ __launch_bounds__(512) void k_psi_bulk(
    const uint16_t* __restrict__ Zg,
    const uint16_t* __restrict__ wb1, const uint16_t* __restrict__ wb2,
    const uint16_t* __restrict__ wb3, const uint16_t* __restrict__ wb4,
    const uint16_t* __restrict__ wb5,
    const float* __restrict__ b1, const float* __restrict__ b2,
    const float* __restrict__ b3, const float* __restrict__ b4,
    const float* __restrict__ b5, float* __restrict__ out)
{
    __shared__ uint16_t hbuf[32 * 1024];   // 64 KB, swizzled
    int tid = threadIdx.x;
    int w = tid >> 6, L = tid & 63, lm = L & 15, q = L >> 4;
    int rb = blockIdx.x * 32;
    int colbase = w * 128;
    floatx4 acc[2][8];
    const floatx4 zero = {0.f, 0.f, 0.f, 0.f};

    // ---- L1: K=256, A straight from global Z
    #pragma unroll
    for (int mt = 0; mt < 2; mt++)
        #pragma unroll
        for (int nt = 0; nt < 8; nt++) acc[mt][nt] = zero;
    for (int kc = 0; kc < 8; kc++) {
        short8 a0 = *(const short8*)(Zg + (size_t)(rb + lm) * LAT + kc * 32 + q * 8);
        short8 a1 = *(const short8*)(Zg + (size_t)(rb + 16 + lm) * LAT + kc * 32 + q * 8);
        #pragma unroll
        for (int nt = 0; nt < 8; nt++) {
            int n = colbase + nt * 16 + lm;
            short8 bf = *(const short8*)(wb1 + (size_t)n * LAT + kc * 32 + q * 8);
            acc[0][nt] = __builtin_amdgcn_mfma_f32_16x16x32_bf16(a0, bf, acc[0][nt], 0, 0, 0);
            acc[1][nt] = __builtin_amdgcn_mfma_f32_16x16x32_bf16(a1, bf, acc[1][nt], 0, 0, 0);
        }
    }
    #pragma unroll
    for (int mt = 0; mt < 2; mt++)
        #pragma unroll
        for (int nt = 0; nt < 8; nt++) {
            int col = colbase + nt * 16 + lm;
            float bias = b1[col];
            #pragma unroll
            for (int i = 0; i < 4; i++) {
                int row = mt * 16 + q * 4 + i;
                hbuf[hswz(row, col)] = f2bf(fmaxf(acc[mt][nt][i] + bias, 0.f));
            }
        }
    __syncthreads();

    // ---- L2..L4: K=1024, in-place hbuf (compute -> sync -> write -> sync)
    const uint16_t* wbs[3] = {wb2, wb3, wb4};
    const float*    bbs[3] = {b2, b3, b4};
    for (int ll = 0; ll < 3; ll++) {
        const uint16_t* wb = wbs[ll];
        const float* bb = bbs[ll];
        #pragma unroll
        for (int mt = 0; mt < 2; mt++)
            #pragma unroll
            for (int nt = 0; nt < 8; nt++) acc[mt][nt] = zero;
        for (int kc = 0; kc < 32; kc++) {
            int g = ((kc * 4 + q) ^ (lm & 7)) << 3;
            short8 a0 = *(const short8*)(hbuf + lm * 1024 + g);
            short8 a1 = *(const short8*)(hbuf + (16 + lm) * 1024 + g);
            #pragma unroll
            for (int nt = 0; nt < 8; nt++) {
                int n = colbase + nt * 16 + lm;
                short8 bf = *(const short8*)(wb + (size_t)n * HID + kc * 32 + q * 8);
                acc[0][nt] = __builtin_amdgcn_mfma_f32_16x16x32_bf16(a0, bf, acc[0][nt], 0, 0, 0);
                acc[1][nt] = __builtin_amdgcn_mfma_f32_16x16x32_bf16(a1, bf, acc[1][nt], 0, 0, 0);
            }
        }
        __syncthreads();
        #pragma unroll
        for (int mt = 0; mt < 2; mt++)
            #pragma unroll
            for (int nt = 0; nt < 8; nt++) {
                int col = colbase + nt * 16 + lm;
                float bias = bb[col];
                #pragma unroll
                for (int i = 0; i < 4; i++) {
                    int row = mt * 16 + q * 4 + i;
                    hbuf[hswz(row, col)] = f2bf(fmaxf(acc[mt][nt][i] + bias, 0.f));
                }
            }
        __syncthreads();
    }

    // ---- L5: 32 outputs, waves 0..3 (mt = w>>1, ntile = w&1)
    if (w < 4) {
        int mt = w >> 1;
        int nb = (w & 1) * 16;
        floatx4 a5 = zero;
        for (int kc = 0; kc < 32; kc++) {
            int g = ((kc * 4 + q) ^ (lm & 7)) << 3;
            short8 a = *(const short8*)(hbuf + (mt * 16 + lm) * 1024 + g);
            short8 bf = *(const short8*)(wb5 + (size_t)(nb + lm) * HID + kc * 32 + q * 8);
            a5 = __builtin_amdgcn_mfma_f32_16x16x32_bf16(a, bf, a5, 0, 0, 0);
        }
        int col = nb + lm;
        float bias = b5[col];
        #pragma unroll
        for (int i = 0; i < 4; i++) {
            int row = mt * 16 + q * 4 + i;
            int r = rb + row;
            int bb_ = r >> 8, tt = r & 255;
            out[(size_t)bb_ * (HOR * OBS) + tt * OBS + col] = a5[i] + bias;
        }
    }
}

// ---------------------------------------------------------------------------
// K3: autoregressive phase. 8 blocks x 16 rows x 512 threads, 256 steps.
// ---------------------------------------------------------------------------
__global__ __launch_bounds__(512) void k_ar(
    const float* __restrict__ zfinal,
    const uint16_t* __restrict__ wb1, const uint16_t* __restrict__ wb2,
    const uint16_t* __restrict__ wb3, const uint16_t* __restrict__ wb4,
    const uint16_t* __restrict__ wb5,
    const uint16_t* __restrict__ wbhh, const uint16_t* __restrict__ wbih,
    const float* __restrict__ b1, const float* __restrict__ b2,
    const float* __restrict__ b3, const float* __restrict__ b4,
    const float* __restrict__ b5, const float* __restrict__ cb,
    float* __restrict__ out)
{
    __shared__ uint16_t hbuf[16 * 1024];   // 32 KB, swizzled
    __shared__ uint16_t zu[16 * 296];      // [z(256) | yh(32) | pad], stride 296
    int tid = threadIdx.x;
    int w = tid >> 6, L = tid & 63, lm = L & 15, q = L >> 4;
    int rb = blockIdx.x * 16;
    int colbase = w * 128;
    const floatx4 zero = {0.f, 0.f, 0.f, 0.f};

    for (int idx = tid; idx < 16 * 256; idx += 512) {
        int m = idx >> 8, k = idx & 255;
        zu[m * 296 + k] = f2bf(zfinal[(size_t)(rb + m) * LAT + k]);
    }
    __syncthreads();

    const uint16_t* wbs[3] = {wb2, wb3, wb4};
    const float*    bbs[3] = {b2, b3, b4};

    #pragma unroll 1
    for (int t = 0; t < HOR - TTF; t++) {
        floatx4 acc[8];
        // ---- L1: K=256 from zu
        #pragma unroll
        for (int nt = 0; nt < 8; nt++) acc[nt] = zero;
        for (int kc = 0; kc < 8; kc++) {
            short8 a = *(const short8*)(zu + lm * 296 + kc * 32 + q * 8);
            #pragma unroll
            for (int nt = 0; nt < 8; nt++) {
                int n = colbase + nt * 16 + lm;
                short8 bf = *(const short8*)(wb1 + (size_t)n * LAT + kc * 32 + q * 8);
                acc[nt] = __builtin_amdgcn_mfma_f32_16x16x32_bf16(a, bf, acc[nt], 0, 0, 0);
            }
        }
        #pragma unroll
        for (int nt = 0; nt < 8; nt++) {
            int col = colbase + nt * 16 + lm;
            float bias = b1[col];
            #pragma unroll
            for (int i = 0; i < 4; i++) {
                int row = q * 4 + i;
                hbuf[hswz(row, col)] = f2bf(fmaxf(acc[nt][i] + bias, 0.f));
            }
        }
        __syncthreads();

        // ---- L2..L4
        for (int ll = 0; ll < 3; ll++) {
            const uint16_t* wb = wbs[ll];
            const float* bb = bbs[ll];
            #pragma unroll
            for (int nt = 0; nt < 8; nt++) acc[nt] = zero;
            for (int kc = 0; kc < 32; kc++) {
                int g = ((kc * 4 + q) ^ (lm & 7)) << 3;
                short8 a = *(const short8*)(hbuf + lm * 1024 + g);
                #pragma unroll
                for (int nt = 0; nt < 8; nt++) {
                    int n = colbase + nt * 16 + lm;
                    short8 bf = *(const short8*)(wb + (size_t)n * HID + kc * 32 + q * 8);
                    acc[nt] = __builtin_amdgcn_mfma_f32_16x16x32_bf16(a, bf, acc[nt], 0, 0, 0);
                }
            }
            __syncthreads();
            #pragma unroll
            for (int nt = 0; nt < 8; nt++) {
                int col = colbase + nt * 16 + lm;
                float bias = bb[col];
                #pragma unroll
                for (int i = 0; i < 4; i++) {
                    int row = q * 4 + i;
                    hbuf[hswz(row, col)] = f2bf(fmaxf(acc[nt][i] + bias, 0.f));
                }
            }
            __syncthreads();
        }

        // ---- L5: waves 0,1 -> yh (to out fp32 + zu bf16)
        if (w < 2) {
            int nb = w * 16;
            floatx4 a5 = zero;
            for (int kc = 0; kc < 32; kc++) {
                int g = ((kc * 4 + q) ^ (lm & 7)) << 3;
                short8 a = *(const short8*)(hbuf + lm * 1024 + g);
                short8 bf = *(const short8*)(wb5 + (size_t)(nb + lm) * HID + kc * 32 + q * 8);
                a5 = __builtin_amdgcn_mfma_f32_16x16x32_bf16(a, bf, a5, 0, 0, 0);
            }
            int col = nb + lm;
            float bias = b5[col];
            #pragma unroll
            for (int i = 0; i < 4; i++) {
                int row = q * 4 + i;
                float v = a5[i] + bias;
                out[(size_t)(rb + row) * (HOR * OBS) + (TTF + t) * OBS + col] = v;
                zu[row * 296 + 256 + col] = f2bf(v);
            }
        }
        __syncthreads();   // yh visible to everyone

        // ---- cell: z' = tanh(W_hh z + W_ih yh + cb), K=288 (9 chunks)
        floatx4 c0 = zero, c1 = zero;
        int n0 = w * 32 + lm, n1 = w * 32 + 16 + lm;
        for (int kc = 0; kc < 9; kc++) {
            short8 a = *(const short8*)(zu + lm * 296 + kc * 32 + q * 8);
            short8 bf0, bf1;
            if (kc < 8) {
                bf0 = *(const short8*)(wbhh + (size_t)n0 * LAT + kc * 32 + q * 8);
                bf1 = *(const short8*)(wbhh + (size_t)n1 * LAT + kc * 32 + q * 8);
            } else {
                bf0 = *(const short8*)(wbih + (size_t)n0 * OBS + q * 8);
                bf1 = *(const short8*)(wbih + (size_t)n1 * OBS + q * 8);
            }
            c0 = __builtin_amdgcn_mfma_f32_16x16x32_bf16(a, bf0, c0, 0, 0, 0);
            c1 = __builtin_amdgcn_mfma_f32_16x16x32_bf16(a, bf1, c1, 0, 0, 0);
        }
        __syncthreads();   // all zu reads done
        float cb0 = cb[n0], cb1 = cb[n1];
        #pragma unroll
        for (int i = 0; i < 4; i++) {
            int row = q * 4 + i;
            zu[row * 296 + n0] = f2bf(fast_tanh(c0[i] + cb0));
            zu[row * 296 + n1] = f2bf(fast_tanh(c1[i] + cb1));
        }
        __syncthreads();   // z' visible for next step
    }
}

// ---------------------------------------------------------------------------
extern "C" void kernel_launch(void* const* d_in, const int* in_sizes, int n_in,
                              void* d_out, int out_size, void* d_ws, size_t ws_size,
                              hipStream_t stream) {
    (void)in_sizes; (void)n_in; (void)out_size; (void)ws_size;
    const float* y    = (const float*)d_in[0];
    const float* W_ih = (const float*)d_in[2];
    const float* W_hh = (const float*)d_in[3];
    const float* b_ih = (const float*)d_in[4];
    const float* b_hh = (const float*)d_in[5];
    const float* W1   = (const float*)d_in[6];
    const float* b1   = (const float*)d_in[7];
    const float* W2   = (const float*)d_in[8];
    const float* b2   = (const float*)d_in[9];
    const float* W3   = (const float*)d_in[10];
    const float* b3   = (const float*)d_in[11];
    const float* W4   = (const float*)d_in[12];
    const float* b4   = (const float*)d_in[13];
    const float* W5   = (const float*)d_in[14];
    const float* b5   = (const float*)d_in[15];
    float* out = (float*)d_out;
    char* ws = (char*)d_ws;

    uint16_t* WB1  = (uint16_t*)(ws + OFF_WB1);
    uint16_t* WB2  = (uint16_t*)(ws + OFF_WB2);
    uint16_t* WB3  = (uint16_t*)(ws + OFF_WB3);
    uint16_t* WB4  = (uint16_t*)(ws + OFF_WB4);
    uint16_t* WB5  = (uint16_t*)(ws + OFF_WB5);
    uint16_t* WBHH = (uint16_t*)(ws + OFF_WBHH);
    uint16_t* WBIH = (uint16_t*)(ws + OFF_WBIH);
    float*    CB   = (float*)(ws + OFF_CB);
    uint2*    WHH2 = (uint2*)(ws + OFF_WHH2);
    uint2*    WIH2 = (uint2*)(ws + OFF_WIH2);
    float*    ZF   = (float*)(ws + OFF_ZF);
    uint16_t* Zbuf = (uint16_t*)(ws + OFF_Z);

    // K0: convert / pack weights (rebuilt every call; ws is re-poisoned)
    k_cvt<<<(HID*LAT + 255) / 256, 256, 0, stream>>>(W1, WB1, HID * LAT);
    k_cvt<<<(HID*HID + 255) / 256, 256, 0, stream>>>(W2, WB2, HID * HID);
    k_cvt<<<(HID*HID + 255) / 256, 256, 0, stream>>>(W3, WB3, HID * HID);
    k_cvt<<<(HID*HID + 255) / 256, 256, 0, stream>>>(W4, WB4, HID * HID);
    k_cvt<<<(OBS*HID + 255) / 256, 256, 0, stream>>>(W5, WB5, OBS * HID);
    k_cvt<<<(LAT*LAT + 255) / 256, 256, 0, stream>>>(W_hh, WBHH, LAT * LAT);
    k_cvt<<<(LAT*OBS + 255) / 256, 256, 0, stream>>>(W_ih, WBIH, LAT * OBS);
    k_cb<<<1, 256, 0, stream>>>(b_ih, b_hh, CB);
    k_pack<<<64, 256, 0, stream>>>(W_hh, WHH2, LAT);
    k_pack<<<8, 256, 0, stream>>>(W_ih, WIH2, OBS);

    // K1: teacher-forced recurrence (z states -> Zbuf, final z -> ZF)
    k_rnn_tf<<<BATCH, 256, 0, stream>>>(y, WHH2, WIH2, CB, Zbuf, ZF);

    // K2: bulk psi over all 32768 phase-1 states -> out[:, 0:256, :]
    k_psi_bulk<<<(BATCH * TTF) / 32, 512, 0, stream>>>(
        Zbuf, WB1, WB2, WB3, WB4, WB5, b1, b2, b3, b4, b5, out);

    // K3: autoregressive rollout -> out[:, 256:512, :]
    k_ar<<<BATCH / 16, 512, 0, stream>>>(
        ZF, WB1, WB2, WB3, WB4, WB5, WBHH, WBIH,
        b1, b2, b3, b4, b5, CB, out);
}

// Round 2
// 14158.722 us; speedup vs baseline: 4.6219x; 4.6219x over previous
//
#include <hip/hip_runtime.h>
#include <stdint.h>

// ---------------------------------------------------------------------------
// RNN rollout. Phase 1: teacher-forced recurrence (cell only) + bulk batched
// psi. Phase 2 (the former bottleneck): persistent cooperative kernel,
// 8 groups x 32 members (256 blocks, 1/CU). Each member owns a 32-col slice
// of every layer; 5 device-scope flag barriers per step; W2 slice resident in
// LDS, other slices stream from L2 (~130 KB/step/CU instead of 6.7 MB).
// Sizes fixed: B=128, T=256, HOR=512, OBS=32, LAT=256, HID=1024.
// ---------------------------------------------------------------------------

#define BATCH 128
#define TTF   256
#define HOR   512
#define OBS   32
#define LAT   256
#define HID   1024

#define GROUPS  8
#define MEMBERS 32
#define ARBLOCKS (GROUPS * MEMBERS)
#define ARTHREADS 128

typedef __attribute__((ext_vector_type(8))) short short8;
typedef __attribute__((ext_vector_type(4))) float floatx4;

// ---- workspace layout (bytes) ----
#define OFF_WB1   ((size_t)0)                          // 1024x256 bf16 (col-major slices: [col][k])
#define OFF_WB2   (OFF_WB1 + (size_t)HID*LAT*2)        // 1024x1024 bf16
#define OFF_WB3   (OFF_WB2 + (size_t)HID*HID*2)
#define OFF_WB4   (OFF_WB3 + (size_t)HID*HID*2)
#define OFF_WB5   (OFF_WB4 + (size_t)HID*HID*2)        // 32x1024 bf16
#define OFF_WBHH  (OFF_WB5 + (size_t)OBS*HID*2)        // 256x256 bf16 (k_rnn_tf only legacy)
#define OFF_WBIH  (OFF_WBHH + (size_t)LAT*LAT*2)       // 256x32 bf16
#define OFF_CB    (OFF_WBIH + (size_t)LAT*OBS*2)       // 256 f32 (b_ih+b_hh)
#define OFF_WHH2  (OFF_CB + (size_t)LAT*4)             // 64x256 uint2 packed W_hh^T
#define OFF_WIH2  (OFF_WHH2 + (size_t)64*256*8)        // 8x256 uint2 packed W_ih^T
#define OFF_ZF    (OFF_WIH2 + (size_t)8*256*8)         // 128x256 f32 (z after phase 1)
#define OFF_Z     (OFF_ZF + (size_t)BATCH*LAT*4)       // 32768x256 bf16 (z_t states)
#define OFF_WBC   (OFF_Z + (size_t)BATCH*TTF*LAT*2)    // 256x288 bf16 [Whh|Wih]^T cell matrix
#define OFF_HB    (OFF_WBC + (size_t)LAT*288*2)        // 8 groups x 4 layers x 16x1024 bf16
#define OFF_ZB    (OFF_HB + (size_t)GROUPS*4*16*HID*2) // 8 groups x 2 x 16x256 bf16 (z dbuf)
#define OFF_CTR   (OFF_ZB + (size_t)GROUPS*2*16*LAT*2) // 8 x 128B barrier counters
#define OFF_END   (OFF_CTR + (size_t)GROUPS*128)

__device__ __forceinline__ uint16_t f2bf(float f) {
    uint32_t u = __float_as_uint(f);
    u += 0x7fffu + ((u >> 16) & 1u);   // RNE
    return (uint16_t)(u >> 16);
}
__device__ __forceinline__ float bflo(uint32_t u) { return __uint_as_float(u << 16); }
__device__ __forceinline__ float bfhi(uint32_t u) { return __uint_as_float(u & 0xffff0000u); }

__device__ __forceinline__ float fast_tanh(float x) {
    float ax = fabsf(x);
    float e  = __expf(-2.f * ax);
    float r  = (1.f - e) / (1.f + e);
    return copysignf(r, x);
}

// swizzled LDS address for psi-bulk h buffers
__device__ __forceinline__ int hswz(int row, int col) {
    return row * 1024 + ((((col >> 3) ^ (row & 7)) << 3) | (col & 7));
}

// group barrier: monotonic counter, relaxed poll + one acquire fence
// (avoids a cache-inv per poll iteration)
__device__ __forceinline__ void gbar(unsigned* ctr, unsigned target) {
    __syncthreads();
    if (threadIdx.x == 0) {
        __hip_atomic_fetch_add(ctr, 1u, __ATOMIC_RELEASE, __HIP_MEMORY_SCOPE_AGENT);
        while (__hip_atomic_load(ctr, __ATOMIC_RELAXED, __HIP_MEMORY_SCOPE_AGENT) < target) {}
        __builtin_amdgcn_fence(__ATOMIC_ACQUIRE, "agent");
    }
    __syncthreads();
}

// ---------------------------------------------------------------------------
// K0 helpers: weight conversion / packing
// ---------------------------------------------------------------------------
__global__ void k_cvt(const float* __restrict__ s, uint16_t* __restrict__ d, int n) {
    int i = blockIdx.x * 256 + threadIdx.x;
    if (i < n) d[i] = f2bf(s[i]);
}

__global__ void k_cb(const float* __restrict__ a, const float* __restrict__ b,
                     float* __restrict__ c) {
    int j = threadIdx.x;
    c[j] = a[j] + b[j];
}

// pack W^T in k4-major uint2: dst[k4*256+j] = bf16(W[j][4k4..4k4+3])
__global__ void k_pack(const float* __restrict__ w, uint2* __restrict__ dst, int klen) {
    int k4 = blockIdx.x, j = threadIdx.x;
    int k = k4 * 4;
    uint32_t a = f2bf(w[(size_t)j * klen + k + 0]);
    uint32_t b = f2bf(w[(size_t)j * klen + k + 1]);
    uint32_t c = f2bf(w[(size_t)j * klen + k + 2]);
    uint32_t d = f2bf(w[(size_t)j * klen + k + 3]);
    uint2 r; r.x = a | (b << 16); r.y = c | (d << 16);
    dst[k4 * 256 + j] = r;
}

// cell matrix [Whh | Wih] as [col][k], K=288
__global__ void k_packc(const float* __restrict__ whh, const float* __restrict__ wih,
                        uint16_t* __restrict__ wbc) {
    int col = blockIdx.x;
    for (int k = threadIdx.x; k < 288; k += 256) {
        float v = (k < 256) ? whh[(size_t)col * 256 + k] : wih[(size_t)col * 32 + (k - 256)];
        wbc[(size_t)col * 288 + k] = f2bf(v);
    }
}

// ---------------------------------------------------------------------------
// K1: teacher-forced recurrence. 128 blocks (1 batch row) x 256 threads.
// ---------------------------------------------------------------------------
__global__ __launch_bounds__(256) void k_rnn_tf(
    const float* __restrict__ y, const uint2* __restrict__ whh2,
    const uint2* __restrict__ wih2, const float* __restrict__ cb,
    uint16_t* __restrict__ Zg, float* __restrict__ zfinal)
{
    __shared__ alignas(16) float zl[LAT];
    __shared__ alignas(16) float ys[OBS];
    int j = threadIdx.x, b = blockIdx.x;
    zl[j] = 0.f;
    __syncthreads();
    const float4* z4 = (const float4*)zl;
    const float4* y4 = (const float4*)ys;
    for (int t = 0; t < TTF; t++) {
        if (j < OBS) ys[j] = y[(size_t)b * (TTF * OBS) + t * OBS + j];
        Zg[((size_t)b * TTF + t) * LAT + j] = f2bf(zl[j]);
        __syncthreads();
        float acc = cb[j];
        #pragma unroll 8
        for (int k4 = 0; k4 < 64; k4++) {
            uint2 wv = whh2[k4 * 256 + j];
            float4 zq = z4[k4];
            acc += bflo(wv.x) * zq.x + bfhi(wv.x) * zq.y
                 + bflo(wv.y) * zq.z + bfhi(wv.y) * zq.w;
        }
        #pragma unroll
        for (int k4 = 0; k4 < 8; k4++) {
            uint2 wv = wih2[k4 * 256 + j];
            float4 yq = y4[k4];
            acc += bflo(wv.x) * yq.x + bfhi(wv.x) * yq.y
                 + bflo(wv.y) * yq.z + bfhi(wv.y) * yq.w;
        }
        __syncthreads();
        zl[j] = fast_tanh(acc);
    }
    __syncthreads();
    zfinal[(size_t)b * LAT + j] = zl[j];
}

// ---------------------------------------------------------------------------
// K2: bulk psi over all 32768 phase-1 states. 1024 blocks x 32 rows, 512 thr.
// ---------------------------------------------------------------------------
__global__ __launch_bounds__(512) void k_psi_bulk(
    const uint16_t* __restrict__ Zg,
    const uint16_t* __restrict__ wb1, const uint16_t* __restrict__ wb2,
    const uint16_t* __restrict__ wb3, const uint16_t* __restrict__ wb4,
    const uint16_t* __restrict__ wb5,
    const float* __restrict__ b1, const float* __restrict__ b2,
    const float* __restrict__ b3, const float* __restrict__ b4,
    const float* __restrict__ b5, float* __restrict__ out)
{
    __shared__ uint16_t hbuf[32 * 1024];   // 64 KB, swizzled
    int tid = threadIdx.x;
    int w = tid >> 6, L = tid & 63, lm = L & 15, q = L >> 4;
    int rb = blockIdx.x * 32;
    int colbase = w * 128;
    floatx4 acc[2][8];
    const floatx4 zero = {0.f, 0.f, 0.f, 0.f};

    #pragma unroll
    for (int mt = 0; mt < 2; mt++)
        #pragma unroll
        for (int nt = 0; nt < 8; nt++) acc[mt][nt] = zero;
    for (int kc = 0; kc < 8; kc++) {
        short8 a0 = *(const short8*)(Zg + (size_t)(rb + lm) * LAT + kc * 32 + q * 8);
        short8 a1 = *(const short8*)(Zg + (size_t)(rb + 16 + lm) * LAT + kc * 32 + q * 8);
        #pragma unroll
        for (int nt = 0; nt < 8; nt++) {
            int n = colbase + nt * 16 + lm;
            short8 bf = *(const short8*)(wb1 + (size_t)n * LAT + kc * 32 + q * 8);
            acc[0][nt] = __builtin_amdgcn_mfma_f32_16x16x32_bf16(a0, bf, acc[0][nt], 0, 0, 0);
            acc[1][nt] = __builtin_amdgcn_mfma_f32_16x16x32_bf16(a1, bf, acc[1][nt], 0, 0, 0);
        }
    }
    #pragma unroll
    for (int mt = 0; mt < 2; mt++)
        #pragma unroll
        for (int nt = 0; nt < 8; nt++) {
            int col = colbase + nt * 16 + lm;
            float bias = b1[col];
            #pragma unroll
            for (int i = 0; i < 4; i++) {
                int row = mt * 16 + q * 4 + i;
                hbuf[hswz(row, col)] = f2bf(fmaxf(acc[mt][nt][i] + bias, 0.f));
            }
        }
    __syncthreads();

    const uint16_t* wbs[3] = {wb2, wb3, wb4};
    const float*    bbs[3] = {b2, b3, b4};
    for (int ll = 0; ll < 3; ll++) {
        const uint16_t* wb = wbs[ll];
        const float* bb = bbs[ll];
        #pragma unroll
        for (int mt = 0; mt < 2; mt++)
            #pragma unroll
            for (int nt = 0; nt < 8; nt++) acc[mt][nt] = zero;
        for (int kc = 0; kc < 32; kc++) {
            int g = ((kc * 4 + q) ^ (lm & 7)) << 3;
            short8 a0 = *(const short8*)(hbuf + lm * 1024 + g);
            short8 a1 = *(const short8*)(hbuf + (16 + lm) * 1024 + g);
            #pragma unroll
            for (int nt = 0; nt < 8; nt++) {
                int n = colbase + nt * 16 + lm;
                short8 bf = *(const short8*)(wb + (size_t)n * HID + kc * 32 + q * 8);
                acc[0][nt] = __builtin_amdgcn_mfma_f32_16x16x32_bf16(a0, bf, acc[0][nt], 0, 0, 0);
                acc[1][nt] = __builtin_amdgcn_mfma_f32_16x16x32_bf16(a1, bf, acc[1][nt], 0, 0, 0);
            }
        }
        __syncthreads();
        #pragma unroll
        for (int mt = 0; mt < 2; mt++)
            #pragma unroll
            for (int nt = 0; nt < 8; nt++) {
                int col = colbase + nt * 16 + lm;
                float bias = bb[col];
                #pragma unroll
                for (int i = 0; i < 4; i++) {
                    int row = mt * 16 + q * 4 + i;
                    hbuf[hswz(row, col)] = f2bf(fmaxf(acc[mt][nt][i] + bias, 0.f));
                }
            }
        __syncthreads();
    }

    if (w < 4) {
        int mt = w >> 1;
        int nb = (w & 1) * 16;
        floatx4 a5 = zero;
        for (int kc = 0; kc < 32; kc++) {
            int g = ((kc * 4 + q) ^ (lm & 7)) << 3;
            short8 a = *(const short8*)(hbuf + (mt * 16 + lm) * 1024 + g);
            short8 bf = *(const short8*)(wb5 + (size_t)(nb + lm) * HID + kc * 32 + q * 8);
            a5 = __builtin_amdgcn_mfma_f32_16x16x32_bf16(a, bf, a5, 0, 0, 0);
        }
        int col = nb + lm;
        float bias = b5[col];
        #pragma unroll
        for (int i = 0; i < 4; i++) {
            int row = mt * 16 + q * 4 + i;
            int r = rb + row;
            int bb_ = r >> 8, tt = r & 255;
            out[(size_t)bb_ * (HOR * OBS) + tt * OBS + col] = a5[i] + bias;
        }
    }
}

// ---------------------------------------------------------------------------
// K3 v2: autoregressive phase, persistent cooperative kernel.
// 256 blocks = 8 groups x 32 members, 128 threads (2 waves).
// Group g: rows [16g,16g+16). Member m: cols [32m,32m+32) of every layer.
// Stages per step: L1 | L2 | L3 | L4 | (L5+cell on members 0..7), with
// device-scope group barriers between. W2 slice (kc 0..30) LDS-resident.
// ---------------------------------------------------------------------------
__global__ __launch_bounds__(ARTHREADS) void k_ar2(
    const float* __restrict__ zfinal,
    const uint16_t* __restrict__ wb1, const uint16_t* __restrict__ wb2,
    const uint16_t* __restrict__ wb3, const uint16_t* __restrict__ wb4,
    const uint16_t* __restrict__ wb5, const uint16_t* __restrict__ wbc,
    const float* __restrict__ b1g, const float* __restrict__ b2g,
    const float* __restrict__ b3g, const float* __restrict__ b4g,
    const float* __restrict__ b5g, const float* __restrict__ cb,
    uint16_t* __restrict__ hb_all, uint16_t* __restrict__ zb_all,
    unsigned* __restrict__ ctr_all, float* __restrict__ out)
{
    __shared__ alignas(16) uint16_t w2l[31 * 1024];   // 62 KB: W2 slice kc 0..30
    __shared__ alignas(16) uint16_t yscr[16 * 32];    // 1 KB: yh transpose
    const int tid = threadIdx.x;
    const int g = blockIdx.x & 7, m = blockIdx.x >> 3;  // blockIdx%8 ~ XCD (heuristic)
    const int w = tid >> 6, L = tid & 63, lm = L & 15, q = L >> 4;
    const int colbase = m * 32;
    const int cl = w * 16 + lm;           // local col 0..31 (wave = N-tile)
    const int rb = g * 16;
    uint16_t* hb = hb_all + (size_t)g * (4 * 16 * HID);
    uint16_t* zb = zb_all + (size_t)g * (2 * 16 * LAT);
    unsigned* ctr = ctr_all + g * 32;     // 128B-spaced counters
    const floatx4 zero = {0.f, 0.f, 0.f, 0.f};

    // preload W2 slice into LDS: layout [kc][c][k%32] (conflict-free b-frags)
    for (int idx = tid; idx < 31 * 32 * 4; idx += ARTHREADS) {
        int kc = idx >> 7, r = idx & 127, c = r >> 2, qq = r & 3;
        *(short8*)(w2l + kc * 1024 + c * 32 + qq * 8) =
            *(const short8*)(wb2 + (size_t)(colbase + c) * HID + kc * 32 + qq * 8);
    }
    // member 0: convert zfinal -> z buffer parity 0
    if (m == 0) {
        for (int idx = tid; idx < 16 * 256; idx += ARTHREADS) {
            int r = idx >> 8, c = idx & 255;
            zb[r * 256 + c] = f2bf(zfinal[(size_t)(rb + r) * LAT + c]);
        }
    }
    unsigned tgt = 0;
    gbar(ctr, tgt += MEMBERS);

    uint16_t* h1 = hb;
    uint16_t* h2 = hb + 16 * HID;
    uint16_t* h3 = hb + 2 * 16 * HID;
    uint16_t* h4 = hb + 3 * 16 * HID;

    #pragma unroll 1
    for (int t = 0; t < HOR - TTF; t++) {
        const uint16_t* zcur = zb + (t & 1) * (16 * 256);
        uint16_t* znext = zb + ((t + 1) & 1) * (16 * 256);

        // ---- L1: h1 = relu(z @ W1s + b1)
        {
            floatx4 acc = zero;
            const uint16_t* ab = zcur + lm * 256 + q * 8;
            const uint16_t* bb = wb1 + (size_t)(colbase + cl) * LAT + q * 8;
            #pragma unroll
            for (int kc = 0; kc < 8; kc++) {
                short8 a = *(const short8*)(ab + kc * 32);
                short8 b = *(const short8*)(bb + kc * 32);
                acc = __builtin_amdgcn_mfma_f32_16x16x32_bf16(a, b, acc, 0, 0, 0);
            }
            int col = colbase + cl;
            float bias = b1g[col];
            #pragma unroll
            for (int i = 0; i < 4; i++)
                h1[(q * 4 + i) * HID + col] = f2bf(fmaxf(acc[i] + bias, 0.f));
        }
        gbar(ctr, tgt += MEMBERS);

        // ---- L2: LDS-resident W2 (kc 0..30) + streamed tail (kc 31)
        {
            floatx4 acc = zero;
            const uint16_t* ab = h1 + lm * HID + q * 8;
            const uint16_t* bl = w2l + cl * 32 + q * 8;
            #pragma unroll 8
            for (int kc = 0; kc < 31; kc++) {
                short8 a = *(const short8*)(ab + kc * 32);
                short8 b = *(const short8*)(bl + kc * 1024);
                acc = __builtin_amdgcn_mfma_f32_16x16x32_bf16(a, b, acc, 0, 0, 0);
            }
            {
                short8 a = *(const short8*)(ab + 31 * 32);
                short8 b = *(const short8*)(wb2 + (size_t)(colbase + cl) * HID + 992 + q * 8);
                acc = __builtin_amdgcn_mfma_f32_16x16x32_bf16(a, b, acc, 0, 0, 0);
            }
            int col = colbase + cl;
            float bias = b2g[col];
            #pragma unroll
            for (int i = 0; i < 4; i++)
                h2[(q * 4 + i) * HID + col] = f2bf(fmaxf(acc[i] + bias, 0.f));
        }
        gbar(ctr, tgt += MEMBERS);

        // ---- L3 (streamed from L2-resident wb3)
        {
            floatx4 acc = zero;
            const uint16_t* ab = h2 + lm * HID + q * 8;
            const uint16_t* bb = wb3 + (size_t)(colbase + cl) * HID + q * 8;
            #pragma unroll 8
            for (int kc = 0; kc < 32; kc++) {
                short8 a = *(const short8*)(ab + kc * 32);
                short8 b = *(const short8*)(bb + kc * 32);
                acc = __builtin_amdgcn_mfma_f32_16x16x32_bf16(a, b, acc, 0, 0, 0);
            }
            int col = colbase + cl;
            float bias = b3g[col];
            #pragma unroll
            for (int i = 0; i < 4; i++)
                h3[(q * 4 + i) * HID + col] = f2bf(fmaxf(acc[i] + bias, 0.f));
        }
        gbar(ctr, tgt += MEMBERS);

        // ---- L4 (streamed from L2-resident wb4)
        {
            floatx4 acc = zero;
            const uint16_t* ab = h3 + lm * HID + q * 8;
            const uint16_t* bb = wb4 + (size_t)(colbase + cl) * HID + q * 8;
            #pragma unroll 8
            for (int kc = 0; kc < 32; kc++) {
                short8 a = *(const short8*)(ab + kc * 32);
                short8 b = *(const short8*)(bb + kc * 32);
                acc = __builtin_amdgcn_mfma_f32_16x16x32_bf16(a, b, acc, 0, 0, 0);
            }
            int col = colbase + cl;
            float bias = b4g[col];
            #pragma unroll
            for (int i = 0; i < 4; i++)
                h4[(q * 4 + i) * HID + col] = f2bf(fmaxf(acc[i] + bias, 0.f));
        }
        gbar(ctr, tgt += MEMBERS);

        // ---- stage 5 (members 0..7): full yh redundantly, then cell slice
        if (m < 8) {
            // L5: wave w computes yh cols [16w,16w+16)
            floatx4 a5 = zero;
            const uint16_t* ab = h4 + lm * HID + q * 8;
            const uint16_t* bb = wb5 + (size_t)cl * HID + q * 8;
            #pragma unroll 8
            for (int kc = 0; kc < 32; kc++) {
                short8 a = *(const short8*)(ab + kc * 32);
                short8 b = *(const short8*)(bb + kc * 32);
                a5 = __builtin_amdgcn_mfma_f32_16x16x32_bf16(a, b, a5, 0, 0, 0);
            }
            float bias = b5g[cl];
            float vout[4];
            #pragma unroll
            for (int i = 0; i < 4; i++) {
                float v = a5[i] + bias;
                vout[i] = v;
                yscr[(q * 4 + i) * 32 + cl] = f2bf(v);
            }
            if (m == 0) {
                #pragma unroll
                for (int i = 0; i < 4; i++)
                    out[(size_t)(rb + q * 4 + i) * (HOR * OBS) + (TTF + t) * OBS + cl] = vout[i];
            }
            __syncthreads();   // yscr visible block-wide
            // cell: z' cols [32m,32m+32), A = [z | yh] K=288
            floatx4 cc = zero;
            int ccol = m * 32 + cl;
            const uint16_t* bb2 = wbc + (size_t)ccol * 288 + q * 8;
            #pragma unroll
            for (int kc = 0; kc < 9; kc++) {
                short8 a = (kc < 8)
                    ? *(const short8*)(zcur + lm * 256 + kc * 32 + q * 8)
                    : *(const short8*)(yscr + lm * 32 + q * 8);
                short8 b = *(const short8*)(bb2 + kc * 32);
                cc = __builtin_amdgcn_mfma_f32_16x16x32_bf16(a, b, cc, 0, 0, 0);
            }
            float cbv = cb[ccol];
            #pragma unroll
            for (int i = 0; i < 4; i++)
                znext[(q * 4 + i) * 256 + ccol] = f2bf(fast_tanh(cc[i] + cbv));
        }
        gbar(ctr, tgt += MEMBERS);
    }
}

// ---------------------------------------------------------------------------
extern "C" void kernel_launch(void* const* d_in, const int* in_sizes, int n_in,
                              void* d_out, int out_size, void* d_ws, size_t ws_size,
                              hipStream_t stream) {
    (void)in_sizes; (void)n_in; (void)out_size; (void)ws_size;
    const float* y    = (const float*)d_in[0];
    const float* W_ih = (const float*)d_in[2];
    const float* W_hh = (const float*)d_in[3];
    const float* b_ih = (const float*)d_in[4];
    const float* b_hh = (const float*)d_in[5];
    const float* W1   = (const float*)d_in[6];
    const float* b1   = (const float*)d_in[7];
    const float* W2   = (const float*)d_in[8];
    const float* b2   = (const float*)d_in[9];
    const float* W3   = (const float*)d_in[10];
    const float* b3   = (const float*)d_in[11];
    const float* W4   = (const float*)d_in[12];
    const float* b4   = (const float*)d_in[13];
    const float* W5   = (const float*)d_in[14];
    const float* b5   = (const float*)d_in[15];
    float* out = (float*)d_out;
    char* ws = (char*)d_ws;

    uint16_t* WB1  = (uint16_t*)(ws + OFF_WB1);
    uint16_t* WB2  = (uint16_t*)(ws + OFF_WB2);
    uint16_t* WB3  = (uint16_t*)(ws + OFF_WB3);
    uint16_t* WB4  = (uint16_t*)(ws + OFF_WB4);
    uint16_t* WB5  = (uint16_t*)(ws + OFF_WB5);
    float*    CB   = (float*)(ws + OFF_CB);
    uint2*    WHH2 = (uint2*)(ws + OFF_WHH2);
    uint2*    WIH2 = (uint2*)(ws + OFF_WIH2);
    float*    ZF   = (float*)(ws + OFF_ZF);
    uint16_t* Zbuf = (uint16_t*)(ws + OFF_Z);
    uint16_t* WBC  = (uint16_t*)(ws + OFF_WBC);
    uint16_t* HB   = (uint16_t*)(ws + OFF_HB);
    uint16_t* ZB   = (uint16_t*)(ws + OFF_ZB);
    unsigned* CTR  = (unsigned*)(ws + OFF_CTR);

    // K0: convert / pack weights
    k_cvt<<<(HID*LAT + 255) / 256, 256, 0, stream>>>(W1, WB1, HID * LAT);
    k_cvt<<<(HID*HID + 255) / 256, 256, 0, stream>>>(W2, WB2, HID * HID);
    k_cvt<<<(HID*HID + 255) / 256, 256, 0, stream>>>(W3, WB3, HID * HID);
    k_cvt<<<(HID*HID + 255) / 256, 256, 0, stream>>>(W4, WB4, HID * HID);
    k_cvt<<<(OBS*HID + 255) / 256, 256, 0, stream>>>(W5, WB5, OBS * HID);
    k_cb<<<1, 256, 0, stream>>>(b_ih, b_hh, CB);
    k_pack<<<64, 256, 0, stream>>>(W_hh, WHH2, LAT);
    k_pack<<<8, 256, 0, stream>>>(W_ih, WIH2, OBS);
    k_packc<<<256, 256, 0, stream>>>(W_hh, W_ih, WBC);
    hipMemsetAsync(CTR, 0, GROUPS * 128, stream);

    // K1: teacher-forced recurrence
    k_rnn_tf<<<BATCH, 256, 0, stream>>>(y, WHH2, WIH2, CB, Zbuf, ZF);

    // K2: bulk psi over phase-1 states -> out[:, 0:256, :]
    k_psi_bulk<<<(BATCH * TTF) / 32, 512, 0, stream>>>(
        Zbuf, WB1, WB2, WB3, WB4, WB5, b1, b2, b3, b4, b5, out);

    // K3: persistent cooperative AR rollout -> out[:, 256:512, :]
    void* args[] = {
        (void*)&ZF, (void*)&WB1, (void*)&WB2, (void*)&WB3, (void*)&WB4,
        (void*)&WB5, (void*)&WBC, (void*)&b1, (void*)&b2, (void*)&b3,
        (void*)&b4, (void*)&b5, (void*)&CB, (void*)&HB, (void*)&ZB,
        (void*)&CTR, (void*)&out
    };
    hipLaunchCooperativeKernel((const void*)k_ar2, dim3(ARBLOCKS), dim3(ARTHREADS),
                               args, 0, stream);
}

// Round 3
// 9909.876 us; speedup vs baseline: 6.6035x; 1.4287x over previous
//
#include <hip/hip_runtime.h>
#include <stdint.h>

// ---------------------------------------------------------------------------
// RNN rollout. Phase 1: teacher-forced recurrence (cell only) + bulk batched
// psi. Phase 2: persistent cooperative kernel, 8 groups x 32 members.
// R3 change: all cross-block exchange (h, z) goes through MALL via
// relaxed agent-scope atomics (sc0 sc1 cache-bypass); barriers carry NO
// acquire/release fences -> per-XCD L2 is never invalidated -> weights stay
// L2-resident instead of being re-fetched 13.7 MB/step (R2's bottleneck).
// Sizes fixed: B=128, T=256, HOR=512, OBS=32, LAT=256, HID=1024.
// ---------------------------------------------------------------------------

#define BATCH 128
#define TTF   256
#define HOR   512
#define OBS   32
#define LAT   256
#define HID   1024

#define GROUPS  8
#define MEMBERS 32
#define ARBLOCKS (GROUPS * MEMBERS)
#define ARTHREADS 128

typedef __attribute__((ext_vector_type(8))) short short8;
typedef __attribute__((ext_vector_type(4))) float floatx4;

// ---- workspace layout (bytes) ----
#define OFF_WB1   ((size_t)0)                          // 1024x256 bf16 ([col][k])
#define OFF_WB2   (OFF_WB1 + (size_t)HID*LAT*2)        // 1024x1024 bf16
#define OFF_WB3   (OFF_WB2 + (size_t)HID*HID*2)
#define OFF_WB4   (OFF_WB3 + (size_t)HID*HID*2)
#define OFF_WB5   (OFF_WB4 + (size_t)HID*HID*2)        // 32x1024 bf16
#define OFF_WBHH  (OFF_WB5 + (size_t)OBS*HID*2)
#define OFF_WBIH  (OFF_WBHH + (size_t)LAT*LAT*2)
#define OFF_CB    (OFF_WBIH + (size_t)LAT*OBS*2)       // 256 f32 (b_ih+b_hh)
#define OFF_WHH2  (OFF_CB + (size_t)LAT*4)             // 64x256 uint2 packed W_hh^T
#define OFF_WIH2  (OFF_WHH2 + (size_t)64*256*8)        // 8x256 uint2 packed W_ih^T
#define OFF_ZF    (OFF_WIH2 + (size_t)8*256*8)         // 128x256 f32
#define OFF_Z     (OFF_ZF + (size_t)BATCH*LAT*4)       // 32768x256 bf16
#define OFF_WBC   (OFF_Z + (size_t)BATCH*TTF*LAT*2)    // 256x288 bf16 cell matrix
#define OFF_HB    (OFF_WBC + (size_t)LAT*288*2)        // 8 x 4 x 16x1024 bf16
#define OFF_ZB    (OFF_HB + (size_t)GROUPS*4*16*HID*2) // 8 x 2 x 16x256 bf16
#define OFF_CTR   (OFF_ZB + (size_t)GROUPS*2*16*LAT*2) // 8 x 128B counters
#define OFF_END   (OFF_CTR + (size_t)GROUPS*128)

__device__ __forceinline__ uint16_t f2bf(float f) {
    uint32_t u = __float_as_uint(f);
    u += 0x7fffu + ((u >> 16) & 1u);   // RNE
    return (uint16_t)(u >> 16);
}
__device__ __forceinline__ float bflo(uint32_t u) { return __uint_as_float(u << 16); }
__device__ __forceinline__ float bfhi(uint32_t u) { return __uint_as_float(u & 0xffff0000u); }

__device__ __forceinline__ float fast_tanh(float x) {
    float ax = fabsf(x);
    float e  = __expf(-2.f * ax);
    float r  = (1.f - e) / (1.f + e);
    return copysignf(r, x);
}

__device__ __forceinline__ int hswz(int row, int col) {
    return row * 1024 + ((((col >> 3) ^ (row & 7)) << 3) | (col & 7));
}

// --- MALL-coherent exchange primitives (sc0 sc1 bypass; no L2 inv) ---
union V16 { short8 s; uint64_t u[2]; };

__device__ __forceinline__ short8 aload16(const uint16_t* p) {
    const uint64_t* q = (const uint64_t*)p;
    V16 v;
    v.u[0] = __hip_atomic_load(q + 0, __ATOMIC_RELAXED, __HIP_MEMORY_SCOPE_AGENT);
    v.u[1] = __hip_atomic_load(q + 1, __ATOMIC_RELAXED, __HIP_MEMORY_SCOPE_AGENT);
    return v.s;
}
__device__ __forceinline__ void astore2(uint16_t* p, uint16_t v) {
    __hip_atomic_store(p, v, __ATOMIC_RELAXED, __HIP_MEMORY_SCOPE_AGENT);
}

// group barrier, fence-free: __syncthreads drains vmcnt(0) before s_barrier,
// so all (cache-bypassing) stores are at MALL before the flag add; the flag
// itself is a MALL atomic; consumers' loads also bypass caches -> no
// buffer_inv needed -> weights stay L2-resident.
__device__ __forceinline__ void gbar(unsigned* ctr, unsigned target) {
    __syncthreads();
    if (threadIdx.x == 0) {
        __hip_atomic_fetch_add(ctr, 1u, __ATOMIC_RELAXED, __HIP_MEMORY_SCOPE_AGENT);
        while (__hip_atomic_load(ctr, __ATOMIC_RELAXED, __HIP_MEMORY_SCOPE_AGENT) < target) {}
    }
    __syncthreads();
}

// ---------------------------------------------------------------------------
// K0 helpers
// ---------------------------------------------------------------------------
__global__ void k_cvt(const float* __restrict__ s, uint16_t* __restrict__ d, int n) {
    int i = blockIdx.x * 256 + threadIdx.x;
    if (i < n) d[i] = f2bf(s[i]);
}

__global__ void k_cb(const float* __restrict__ a, const float* __restrict__ b,
                     float* __restrict__ c) {
    int j = threadIdx.x;
    c[j] = a[j] + b[j];
}

__global__ void k_pack(const float* __restrict__ w, uint2* __restrict__ dst, int klen) {
    int k4 = blockIdx.x, j = threadIdx.x;
    int k = k4 * 4;
    uint32_t a = f2bf(w[(size_t)j * klen + k + 0]);
    uint32_t b = f2bf(w[(size_t)j * klen + k + 1]);
    uint32_t c = f2bf(w[(size_t)j * klen + k + 2]);
    uint32_t d = f2bf(w[(size_t)j * klen + k + 3]);
    uint2 r; r.x = a | (b << 16); r.y = c | (d << 16);
    dst[k4 * 256 + j] = r;
}

__global__ void k_packc(const float* __restrict__ whh, const float* __restrict__ wih,
                        uint16_t* __restrict__ wbc) {
    int col = blockIdx.x;
    for (int k = threadIdx.x; k < 288; k += 256) {
        float v = (k < 256) ? whh[(size_t)col * 256 + k] : wih[(size_t)col * 32 + (k - 256)];
        wbc[(size_t)col * 288 + k] = f2bf(v);
    }
}

// ---------------------------------------------------------------------------
// K1: teacher-forced recurrence. 128 blocks x 256 threads.
// ---------------------------------------------------------------------------
__global__ __launch_bounds__(256) void k_rnn_tf(
    const float* __restrict__ y, const uint2* __restrict__ whh2,
    const uint2* __restrict__ wih2, const float* __restrict__ cb,
    uint16_t* __restrict__ Zg, float* __restrict__ zfinal)
{
    __shared__ alignas(16) float zl[LAT];
    __shared__ alignas(16) float ys[OBS];
    int j = threadIdx.x, b = blockIdx.x;
    zl[j] = 0.f;
    __syncthreads();
    const float4* z4 = (const float4*)zl;
    const float4* y4 = (const float4*)ys;
    for (int t = 0; t < TTF; t++) {
        if (j < OBS) ys[j] = y[(size_t)b * (TTF * OBS) + t * OBS + j];
        Zg[((size_t)b * TTF + t) * LAT + j] = f2bf(zl[j]);
        __syncthreads();
        float acc = cb[j];
        #pragma unroll 8
        for (int k4 = 0; k4 < 64; k4++) {
            uint2 wv = whh2[k4 * 256 + j];
            float4 zq = z4[k4];
            acc += bflo(wv.x) * zq.x + bfhi(wv.x) * zq.y
                 + bflo(wv.y) * zq.z + bfhi(wv.y) * zq.w;
        }
        #pragma unroll
        for (int k4 = 0; k4 < 8; k4++) {
            uint2 wv = wih2[k4 * 256 + j];
            float4 yq = y4[k4];
            acc += bflo(wv.x) * yq.x + bfhi(wv.x) * yq.y
                 + bflo(wv.y) * yq.z + bfhi(wv.y) * yq.w;
        }
        __syncthreads();
        zl[j] = fast_tanh(acc);
    }
    __syncthreads();
    zfinal[(size_t)b * LAT + j] = zl[j];
}

// ---------------------------------------------------------------------------
// K2: bulk psi over all 32768 phase-1 states. 1024 blocks x 32 rows, 512 thr.
// ---------------------------------------------------------------------------
__global__ __launch_bounds__(512) void k_psi_bulk(
    const uint16_t* __restrict__ Zg,
    const uint16_t* __restrict__ wb1, const uint16_t* __restrict__ wb2,
    const uint16_t* __restrict__ wb3, const uint16_t* __restrict__ wb4,
    const uint16_t* __restrict__ wb5,
    const float* __restrict__ b1, const float* __restrict__ b2,
    const float* __restrict__ b3, const float* __restrict__ b4,
    const float* __restrict__ b5, float* __restrict__ out)
{
    __shared__ uint16_t hbuf[32 * 1024];   // 64 KB, swizzled
    int tid = threadIdx.x;
    int w = tid >> 6, L = tid & 63, lm = L & 15, q = L >> 4;
    int rb = blockIdx.x * 32;
    int colbase = w * 128;
    floatx4 acc[2][8];
    const floatx4 zero = {0.f, 0.f, 0.f, 0.f};

    #pragma unroll
    for (int mt = 0; mt < 2; mt++)
        #pragma unroll
        for (int nt = 0; nt < 8; nt++) acc[mt][nt] = zero;
    for (int kc = 0; kc < 8; kc++) {
        short8 a0 = *(const short8*)(Zg + (size_t)(rb + lm) * LAT + kc * 32 + q * 8);
        short8 a1 = *(const short8*)(Zg + (size_t)(rb + 16 + lm) * LAT + kc * 32 + q * 8);
        #pragma unroll
        for (int nt = 0; nt < 8; nt++) {
            int n = colbase + nt * 16 + lm;
            short8 bf = *(const short8*)(wb1 + (size_t)n * LAT + kc * 32 + q * 8);
            acc[0][nt] = __builtin_amdgcn_mfma_f32_16x16x32_bf16(a0, bf, acc[0][nt], 0, 0, 0);
            acc[1][nt] = __builtin_amdgcn_mfma_f32_16x16x32_bf16(a1, bf, acc[1][nt], 0, 0, 0);
        }
    }
    #pragma unroll
    for (int mt = 0; mt < 2; mt++)
        #pragma unroll
        for (int nt = 0; nt < 8; nt++) {
            int col = colbase + nt * 16 + lm;
            float bias = b1[col];
            #pragma unroll
            for (int i = 0; i < 4; i++) {
                int row = mt * 16 + q * 4 + i;
                hbuf[hswz(row, col)] = f2bf(fmaxf(acc[mt][nt][i] + bias, 0.f));
            }
        }
    __syncthreads();

    const uint16_t* wbs[3] = {wb2, wb3, wb4};
    const float*    bbs[3] = {b2, b3, b4};
    for (int ll = 0; ll < 3; ll++) {
        const uint16_t* wb = wbs[ll];
        const float* bb = bbs[ll];
        #pragma unroll
        for (int mt = 0; mt < 2; mt++)
            #pragma unroll
            for (int nt = 0; nt < 8; nt++) acc[mt][nt] = zero;
        for (int kc = 0; kc < 32; kc++) {
            int g = ((kc * 4 + q) ^ (lm & 7)) << 3;
            short8 a0 = *(const short8*)(hbuf + lm * 1024 + g);
            short8 a1 = *(const short8*)(hbuf + (16 + lm) * 1024 + g);
            #pragma unroll
            for (int nt = 0; nt < 8; nt++) {
                int n = colbase + nt * 16 + lm;
                short8 bf = *(const short8*)(wb + (size_t)n * HID + kc * 32 + q * 8);
                acc[0][nt] = __builtin_amdgcn_mfma_f32_16x16x32_bf16(a0, bf, acc[0][nt], 0, 0, 0);
                acc[1][nt] = __builtin_amdgcn_mfma_f32_16x16x32_bf16(a1, bf, acc[1][nt], 0, 0, 0);
            }
        }
        __syncthreads();
        #pragma unroll
        for (int mt = 0; mt < 2; mt++)
            #pragma unroll
            for (int nt = 0; nt < 8; nt++) {
                int col = colbase + nt * 16 + lm;
                float bias = bb[col];
                #pragma unroll
                for (int i = 0; i < 4; i++) {
                    int row = mt * 16 + q * 4 + i;
                    hbuf[hswz(row, col)] = f2bf(fmaxf(acc[mt][nt][i] + bias, 0.f));
                }
            }
        __syncthreads();
    }

    if (w < 4) {
        int mt = w >> 1;
        int nb = (w & 1) * 16;
        floatx4 a5 = zero;
        for (int kc = 0; kc < 32; kc++) {
            int g = ((kc * 4 + q) ^ (lm & 7)) << 3;
            short8 a = *(const short8*)(hbuf + (mt * 16 + lm) * 1024 + g);
            short8 bf = *(const short8*)(wb5 + (size_t)(nb + lm) * HID + kc * 32 + q * 8);
            a5 = __builtin_amdgcn_mfma_f32_16x16x32_bf16(a, bf, a5, 0, 0, 0);
        }
        int col = nb + lm;
        float bias = b5[col];
        #pragma unroll
        for (int i = 0; i < 4; i++) {
            int row = mt * 16 + q * 4 + i;
            int r = rb + row;
            int bb_ = r >> 8, tt = r & 255;
            out[(size_t)bb_ * (HOR * OBS) + tt * OBS + col] = a5[i] + bias;
        }
    }
}

// ---------------------------------------------------------------------------
// K3 v3: persistent cooperative AR. 8 groups x 32 members, 128 threads.
// Cross-block h/z exchange via MALL atomics; weights via normal cached loads
// (L2-resident, never invalidated). W2 slice LDS-resident.
// ---------------------------------------------------------------------------
__global__ __launch_bounds__(ARTHREADS) void k_ar2(
    const float* __restrict__ zfinal,
    const uint16_t* __restrict__ wb1, const uint16_t* __restrict__ wb2,
    const uint16_t* __restrict__ wb3, const uint16_t* __restrict__ wb4,
    const uint16_t* __restrict__ wb5, const uint16_t* __restrict__ wbc,
    const float* __restrict__ b1g, const float* __restrict__ b2g,
    const float* __restrict__ b3g, const float* __restrict__ b4g,
    const float* __restrict__ b5g, const float* __restrict__ cb,
    uint16_t* __restrict__ hb_all, uint16_t* __restrict__ zb_all,
    unsigned* __restrict__ ctr_all, float* __restrict__ out)
{
    __shared__ alignas(16) uint16_t w2l[31 * 1024];   // 62 KB
    __shared__ alignas(16) uint16_t yscr[16 * 32];    // 1 KB
    const int tid = threadIdx.x;
    const int g = blockIdx.x & 7, m = blockIdx.x >> 3;  // group ~ XCD (perf heuristic only)
    const int w = tid >> 6, L = tid & 63, lm = L & 15, q = L >> 4;
    const int colbase = m * 32;
    const int cl = w * 16 + lm;
    const int rb = g * 16;
    uint16_t* hb = hb_all + (size_t)g * (4 * 16 * HID);
    uint16_t* zb = zb_all + (size_t)g * (2 * 16 * LAT);
    unsigned* ctr = ctr_all + g * 32;
    const floatx4 zero = {0.f, 0.f, 0.f, 0.f};

    // preload W2 slice into LDS (normal cached loads)
    for (int idx = tid; idx < 31 * 32 * 4; idx += ARTHREADS) {
        int kc = idx >> 7, r = idx & 127, c = r >> 2, qq = r & 3;
        *(short8*)(w2l + kc * 1024 + c * 32 + qq * 8) =
            *(const short8*)(wb2 + (size_t)(colbase + c) * HID + kc * 32 + qq * 8);
    }
    // member 0: zfinal -> z parity 0 (MALL stores)
    if (m == 0) {
        for (int idx = tid; idx < 16 * 256; idx += ARTHREADS) {
            int r = idx >> 8, c = idx & 255;
            astore2(zb + r * 256 + c, f2bf(zfinal[(size_t)(rb + r) * LAT + c]));
        }
    }
    unsigned tgt = 0;
    gbar(ctr, tgt += MEMBERS);

    uint16_t* h1 = hb;
    uint16_t* h2 = hb + 16 * HID;
    uint16_t* h3 = hb + 2 * 16 * HID;
    uint16_t* h4 = hb + 3 * 16 * HID;

    #pragma unroll 1
    for (int t = 0; t < HOR - TTF; t++) {
        uint16_t* zcur = zb + (t & 1) * (16 * 256);
        uint16_t* znext = zb + ((t + 1) & 1) * (16 * 256);

        // ---- L1: h1 = relu(z @ W1s + b1)
        {
            floatx4 acc = zero;
            const uint16_t* ab = zcur + lm * 256 + q * 8;
            const uint16_t* bb = wb1 + (size_t)(colbase + cl) * LAT + q * 8;
            #pragma unroll
            for (int kc = 0; kc < 8; kc++) {
                short8 a = aload16(ab + kc * 32);
                short8 b = *(const short8*)(bb + kc * 32);
                acc = __builtin_amdgcn_mfma_f32_16x16x32_bf16(a, b, acc, 0, 0, 0);
            }
            int col = colbase + cl;
            float bias = b1g[col];
            #pragma unroll
            for (int i = 0; i < 4; i++)
                astore2(h1 + (q * 4 + i) * HID + col, f2bf(fmaxf(acc[i] + bias, 0.f)));
        }
        gbar(ctr, tgt += MEMBERS);

        // ---- L2: LDS-resident W2 (kc 0..30) + streamed tail
        {
            floatx4 acc = zero;
            const uint16_t* ab = h1 + lm * HID + q * 8;
            const uint16_t* bl = w2l + cl * 32 + q * 8;
            #pragma unroll 8
            for (int kc = 0; kc < 31; kc++) {
                short8 a = aload16(ab + kc * 32);
                short8 b = *(const short8*)(bl + kc * 1024);
                acc = __builtin_amdgcn_mfma_f32_16x16x32_bf16(a, b, acc, 0, 0, 0);
            }
            {
                short8 a = aload16(ab + 31 * 32);
                short8 b = *(const short8*)(wb2 + (size_t)(colbase + cl) * HID + 992 + q * 8);
                acc = __builtin_amdgcn_mfma_f32_16x16x32_bf16(a, b, acc, 0, 0, 0);
            }
            int col = colbase + cl;
            float bias = b2g[col];
            #pragma unroll
            for (int i = 0; i < 4; i++)
                astore2(h2 + (q * 4 + i) * HID + col, f2bf(fmaxf(acc[i] + bias, 0.f)));
        }
        gbar(ctr, tgt += MEMBERS);

        // ---- L3
        {
            floatx4 acc = zero;
            const uint16_t* ab = h2 + lm * HID + q * 8;
            const uint16_t* bb = wb3 + (size_t)(colbase + cl) * HID + q * 8;
            #pragma unroll 8
            for (int kc = 0; kc < 32; kc++) {
                short8 a = aload16(ab + kc * 32);
                short8 b = *(const short8*)(bb + kc * 32);
                acc = __builtin_amdgcn_mfma_f32_16x16x32_bf16(a, b, acc, 0, 0, 0);
            }
            int col = colbase + cl;
            float bias = b3g[col];
            #pragma unroll
            for (int i = 0; i < 4; i++)
                astore2(h3 + (q * 4 + i) * HID + col, f2bf(fmaxf(acc[i] + bias, 0.f)));
        }
        gbar(ctr, tgt += MEMBERS);

        // ---- L4
        {
            floatx4 acc = zero;
            const uint16_t* ab = h3 + lm * HID + q * 8;
            const uint16_t* bb = wb4 + (size_t)(colbase + cl) * HID + q * 8;
            #pragma unroll 8
            for (int kc = 0; kc < 32; kc++) {
                short8 a = aload16(ab + kc * 32);
                short8 b = *(const short8*)(bb + kc * 32);
                acc = __builtin_amdgcn_mfma_f32_16x16x32_bf16(a, b, acc, 0, 0, 0);
            }
            int col = colbase + cl;
            float bias = b4g[col];
            #pragma unroll
            for (int i = 0; i < 4; i++)
                astore2(h4 + (q * 4 + i) * HID + col, f2bf(fmaxf(acc[i] + bias, 0.f)));
        }
        gbar(ctr, tgt += MEMBERS);

        // ---- stage 5 (members 0..7): L5 redundant + cell slice
        if (m < 8) {
            floatx4 a5 = zero;
            const uint16_t* ab = h4 + lm * HID + q * 8;
            const uint16_t* bb = wb5 + (size_t)cl * HID + q * 8;
            #pragma unroll 8
            for (int kc = 0; kc < 32; kc++) {
                short8 a = aload16(ab + kc * 32);
                short8 b = *(const short8*)(bb + kc * 32);
                a5 = __builtin_amdgcn_mfma_f32_16x16x32_bf16(a, b, a5, 0, 0, 0);
            }
            float bias = b5g[cl];
            float vout[4];
            #pragma unroll
            for (int i = 0; i < 4; i++) {
                float v = a5[i] + bias;
                vout[i] = v;
                yscr[(q * 4 + i) * 32 + cl] = f2bf(v);
            }
            if (m == 0) {
                #pragma unroll
                for (int i = 0; i < 4; i++)
                    out[(size_t)(rb + q * 4 + i) * (HOR * OBS) + (TTF + t) * OBS + cl] = vout[i];
            }
            __syncthreads();
            floatx4 cc = zero;
            int ccol = m * 32 + cl;
            const uint16_t* bb2 = wbc + (size_t)ccol * 288 + q * 8;
            #pragma unroll
            for (int kc = 0; kc < 9; kc++) {
                short8 a;
                if (kc < 8) a = aload16(zcur + lm * 256 + kc * 32 + q * 8);
                else        a = *(const short8*)(yscr + lm * 32 + q * 8);
                short8 b = *(const short8*)(bb2 + kc * 32);
                cc = __builtin_amdgcn_mfma_f32_16x16x32_bf16(a, b, cc, 0, 0, 0);
            }
            float cbv = cb[ccol];
            #pragma unroll
            for (int i = 0; i < 4; i++)
                astore2(znext + (q * 4 + i) * 256 + ccol, f2bf(fast_tanh(cc[i] + cbv)));
        }
        gbar(ctr, tgt += MEMBERS);
    }
}

// ---------------------------------------------------------------------------
extern "C" void kernel_launch(void* const* d_in, const int* in_sizes, int n_in,
                              void* d_out, int out_size, void* d_ws, size_t ws_size,
                              hipStream_t stream) {
    (void)in_sizes; (void)n_in; (void)out_size; (void)ws_size;
    const float* y    = (const float*)d_in[0];
    const float* W_ih = (const float*)d_in[2];
    const float* W_hh = (const float*)d_in[3];
    const float* b_ih = (const float*)d_in[4];
    const float* b_hh = (const float*)d_in[5];
    const float* W1   = (const float*)d_in[6];
    const float* b1   = (const float*)d_in[7];
    const float* W2   = (const float*)d_in[8];
    const float* b2   = (const float*)d_in[9];
    const float* W3   = (const float*)d_in[10];
    const float* b3   = (const float*)d_in[11];
    const float* W4   = (const float*)d_in[12];
    const float* b4   = (const float*)d_in[13];
    const float* W5   = (const float*)d_in[14];
    const float* b5   = (const float*)d_in[15];
    float* out = (float*)d_out;
    char* ws = (char*)d_ws;

    uint16_t* WB1  = (uint16_t*)(ws + OFF_WB1);
    uint16_t* WB2  = (uint16_t*)(ws + OFF_WB2);
    uint16_t* WB3  = (uint16_t*)(ws + OFF_WB3);
    uint16_t* WB4  = (uint16_t*)(ws + OFF_WB4);
    uint16_t* WB5  = (uint16_t*)(ws + OFF_WB5);
    float*    CB   = (float*)(ws + OFF_CB);
    uint2*    WHH2 = (uint2*)(ws + OFF_WHH2);
    uint2*    WIH2 = (uint2*)(ws + OFF_WIH2);
    float*    ZF   = (float*)(ws + OFF_ZF);
    uint16_t* Zbuf = (uint16_t*)(ws + OFF_Z);
    uint16_t* WBC  = (uint16_t*)(ws + OFF_WBC);
    uint16_t* HB   = (uint16_t*)(ws + OFF_HB);
    uint16_t* ZB   = (uint16_t*)(ws + OFF_ZB);
    unsigned* CTR  = (unsigned*)(ws + OFF_CTR);

    k_cvt<<<(HID*LAT + 255) / 256, 256, 0, stream>>>(W1, WB1, HID * LAT);
    k_cvt<<<(HID*HID + 255) / 256, 256, 0, stream>>>(W2, WB2, HID * HID);
    k_cvt<<<(HID*HID + 255) / 256, 256, 0, stream>>>(W3, WB3, HID * HID);
    k_cvt<<<(HID*HID + 255) / 256, 256, 0, stream>>>(W4, WB4, HID * HID);
    k_cvt<<<(OBS*HID + 255) / 256, 256, 0, stream>>>(W5, WB5, OBS * HID);
    k_cb<<<1, 256, 0, stream>>>(b_ih, b_hh, CB);
    k_pack<<<64, 256, 0, stream>>>(W_hh, WHH2, LAT);
    k_pack<<<8, 256, 0, stream>>>(W_ih, WIH2, OBS);
    k_packc<<<256, 256, 0, stream>>>(W_hh, W_ih, WBC);
    hipMemsetAsync(CTR, 0, GROUPS * 128, stream);

    k_rnn_tf<<<BATCH, 256, 0, stream>>>(y, WHH2, WIH2, CB, Zbuf, ZF);

    k_psi_bulk<<<(BATCH * TTF) / 32, 512, 0, stream>>>(
        Zbuf, WB1, WB2, WB3, WB4, WB5, b1, b2, b3, b4, b5, out);

    void* args[] = {
        (void*)&ZF, (void*)&WB1, (void*)&WB2, (void*)&WB3, (void*)&WB4,
        (void*)&WB5, (void*)&WBC, (void*)&b1, (void*)&b2, (void*)&b3,
        (void*)&b4, (void*)&b5, (void*)&CB, (void*)&HB, (void*)&ZB,
        (void*)&CTR, (void*)&out
    };
    hipLaunchCooperativeKernel((const void*)k_ar2, dim3(ARBLOCKS), dim3(ARTHREADS),
                               args, 0, stream);
}